// Round 6
// baseline (262.399 us; speedup 1.0000x reference)
//
#include <hip/hip_runtime.h>
#include <hip/hip_bf16.h>
#include <math.h>

#define B_  2
#define S_  2048
#define H_  16
#define D_  1024
#define DK_ 64

typedef __attribute__((ext_vector_type(8))) short bf16x8;   // 8 bf16 = 4 VGPRs
typedef __attribute__((ext_vector_type(8))) unsigned short ushort8v;
typedef __attribute__((ext_vector_type(4))) float f32x4;

__device__ __forceinline__ unsigned short f2bf(float f) {
  unsigned u = __float_as_uint(f);
  unsigned r = (u + 0x7FFFu + ((u >> 16) & 1u)) >> 16;   // RNE
  return (unsigned short)r;
}
// truncation pack: two fp32 -> packed bf16x2 (P>=0; relative err ~2^-8, OK)
__device__ __forceinline__ unsigned pack_trunc(float lo, float hi) {
  return (__float_as_uint(lo) >> 16) | (__float_as_uint(hi) & 0xffff0000u);
}
__device__ __forceinline__ float fast_exp2(float x) {
#if __has_builtin(__builtin_amdgcn_exp2f)
  return __builtin_amdgcn_exp2f(x);
#else
  return __expf(x * 0.69314718056f);
#endif
}
// async global->LDS, 16B/lane. LDS dest = wave-uniform base + lane*16.
__device__ __forceinline__ void gload_lds16(const unsigned short* g,
                                            unsigned short* l) {
  __builtin_amdgcn_global_load_lds(
      (const __attribute__((address_space(1))) unsigned int*)(const void*)g,
      (__attribute__((address_space(3))) unsigned int*)(void*)l, 16, 0, 0);
}

// ---------------------------------------------------------------------------
// Cast fp32 -> bf16 for x (2048 blocks) + 4 weights (512 blocks each).
// ---------------------------------------------------------------------------
__global__ __launch_bounds__(256)
void cast5_bf16(const float* __restrict__ x,  const float* __restrict__ wq,
                const float* __restrict__ wk, const float* __restrict__ wv,
                const float* __restrict__ wo,
                unsigned short* __restrict__ xb,  unsigned short* __restrict__ wqb,
                unsigned short* __restrict__ wkb, unsigned short* __restrict__ wvb,
                unsigned short* __restrict__ wob)
{
  const int idx = blockIdx.x;
  const float* s; unsigned short* d; int lblk;
  if (idx < 2048) { s = x; d = xb; lblk = idx; }
  else {
    int t = idx - 2048;
    int w = t >> 9;          // 0..3
    lblk  = t & 511;
    s = (w == 0) ? wq  : (w == 1) ? wk  : (w == 2) ? wv  : wo;
    d = (w == 0) ? wqb : (w == 1) ? wkb : (w == 2) ? wvb : wob;
  }
  size_t i0 = ((size_t)lblk * 256 + threadIdx.x) * 8;
  float4 v0 = *(const float4*)(s + i0);
  float4 v1 = *(const float4*)(s + i0 + 4);
  ushort8v o;
  o[0] = f2bf(v0.x); o[1] = f2bf(v0.y); o[2] = f2bf(v0.z); o[3] = f2bf(v0.w);
  o[4] = f2bf(v1.x); o[5] = f2bf(v1.y); o[6] = f2bf(v1.z); o[7] = f2bf(v1.w);
  *(ushort8v*)(d + i0) = o;
}

// ---------------------------------------------------------------------------
// Fused QKV projection GEMM. 64(M)x128(N) tiles -> 512 blocks per z,
// 24 KB single-buffered LDS. Mod-8 XOR swizzle rows.
// blockIdx.z: 0=Q, 1=K, 2=V (operand swap -> V^T).
// ---------------------------------------------------------------------------
__global__ __launch_bounds__(256)
void gemm_qkv(const unsigned short* __restrict__ A0,
              const unsigned short* __restrict__ W0,
              const unsigned short* __restrict__ W1,
              const unsigned short* __restrict__ W2,
              unsigned short* __restrict__ qh,
              unsigned short* __restrict__ kh,
              unsigned short* __restrict__ vt,
              const int* __restrict__ tp)
{
  const int z    = blockIdx.z;
  const int flat = blockIdx.y * 8 + blockIdx.x;   // 0..511
  const int xcd  = flat & 7;
  const int u    = flat >> 3;                     // 0..63

  int row0, col0;
  if (z < 2) {
    row0 = (xcd * 8 + (u & 7)) * 64;
    col0 = (u >> 3) * 128;
  } else {
    int tc = xcd * 4 + (u & 3);
    int cr = u >> 2;
    row0 = cr * 64;
    col0 = tc * 128;
  }
  const unsigned short* Aptr = (z == 2) ? W2 : A0;
  const unsigned short* Bptr = (z == 0) ? W0 : (z == 1) ? W1 : A0;

  __shared__ unsigned short As[64 * 64];    // 8 KB
  __shared__ unsigned short Bs[128 * 64];   // 16 KB
  __shared__ int tps[64];

  const int tid   = threadIdx.x;
  const int wave  = tid >> 6;
  const int lane  = tid & 63;
  const int quad  = lane >> 4;
  const int col16 = lane & 15;
  const int wr    = (wave >> 1) * 32;
  const int wc    = (wave & 1) * 64;

  if (z < 2 && tid < 64) tps[tid] = tp[row0 + tid];

  const int srow = wave * 8 + (lane >> 3);
  const int scol = ((lane & 7) ^ ((lane >> 3) & 7)) * 8;
  const unsigned short* gA = Aptr + (size_t)(row0 + srow) * D_ + scol;
  const unsigned short* gB = Bptr + (size_t)(col0 + srow) * D_ + scol;

  f32x4 acc[2][4];
  #pragma unroll
  for (int mt = 0; mt < 2; ++mt)
    #pragma unroll
    for (int nt = 0; nt < 4; ++nt)
      #pragma unroll
      for (int r = 0; r < 4; ++r) acc[mt][nt][r] = 0.f;

  for (int k0 = 0; k0 < D_; k0 += 64) {
    __syncthreads();
    #pragma unroll
    for (int p = 0; p < 2; ++p)
      gload_lds16(gA + (size_t)(p * 32) * D_ + k0, &As[(p * 32 + wave * 8) * 64]);
    #pragma unroll
    for (int p = 0; p < 4; ++p)
      gload_lds16(gB + (size_t)(p * 32) * D_ + k0, &Bs[(p * 32 + wave * 8) * 64]);
    __syncthreads();

    #pragma unroll
    for (int h = 0; h < 2; ++h) {
      const int jo = ((h * 4 + quad) ^ (col16 & 7)) * 8;
      bf16x8 af[2], bfr[4];
      #pragma unroll
      for (int mt = 0; mt < 2; ++mt)
        af[mt] = *(const bf16x8*)&As[(wr + mt * 16 + col16) * 64 + jo];
      #pragma unroll
      for (int nt = 0; nt < 4; ++nt)
        bfr[nt] = *(const bf16x8*)&Bs[(wc + nt * 16 + col16) * 64 + jo];

      #pragma unroll
      for (int mt = 0; mt < 2; ++mt)
        #pragma unroll
        for (int nt = 0; nt < 4; ++nt)
          acc[mt][nt] = __builtin_amdgcn_mfma_f32_16x16x32_bf16(
              af[mt], bfr[nt], acc[mt][nt], 0, 0, 0);
    }
  }

  if (z == 2) {
    #pragma unroll
    for (int mt = 0; mt < 2; ++mt)
      #pragma unroll
      for (int r = 0; r < 4; ++r) {
        int c = row0 + wr + mt * 16 + quad * 4 + r;   // channel
        int h = c >> 6, d = c & 63;
        #pragma unroll
        for (int nt = 0; nt < 4; ++nt) {
          int t  = col0 + wc + nt * 16 + col16;       // token
          int bb = t >> 11, sl = t & (S_ - 1);
          vt[((size_t)((bb << 4) + h) * DK_ + d) * S_ + sl] =
              f2bf(acc[mt][nt][r]);
        }
      }
  } else {
    unsigned short* C = z ? kh : qh;
    const float qs = z ? 1.0f : 0.1803368801111204f;  // 0.125*log2(e) for Q
    const float sgn = (col16 & 1) ? 1.f : -1.f;       // even lane: re = v*c - o*s
    float freqr[4];
    #pragma unroll
    for (int nt = 0; nt < 4; ++nt) {
      int i = ((wc + nt * 16 + col16) & 63) >> 1;
      freqr[nt] = exp2f(-0.4152410118f * (float)i);   // 10000^(-2i/64)
    }
    #pragma unroll
    for (int mt = 0; mt < 2; ++mt)
      #pragma unroll
      for (int r = 0; r < 4; ++r) {
        int rl  = wr + mt * 16 + quad * 4 + r;
        int row = row0 + rl;
        float p = (float)tps[rl];
        #pragma unroll
        for (int nt = 0; nt < 4; ++nt) {
          int col = col0 + wc + nt * 16 + col16;
          float ang = p * freqr[nt];
          float sn = __sinf(ang), cs = __cosf(ang);
          float val = acc[mt][nt][r];
          float oth = __shfl_xor(val, 1);
          C[(size_t)row * D_ + col] = f2bf((val * cs + oth * sgn * sn) * qs);
        }
      }
  }
}

// ---------------------------------------------------------------------------
// Wo projection GEMM. 64x64 tiles -> 1024 blocks, 16 KB LDS, bounds(256,8).
// ---------------------------------------------------------------------------
__global__ __launch_bounds__(256, 8)
void gemm_wo(const unsigned short* __restrict__ A,
             const unsigned short* __restrict__ W,
             float* __restrict__ C)
{
  __shared__ unsigned short As[64 * 64];    // 8 KB
  __shared__ unsigned short Bs[64 * 64];    // 8 KB

  const int flat = blockIdx.y * 16 + blockIdx.x;  // 0..1023
  const int xcd  = flat & 7;
  const int u    = flat >> 3;                     // 0..127
  const int by   = xcd * 8 + (u & 7);             // 0..63
  const int bx   = u >> 3;                        // 0..15

  const int tid   = threadIdx.x;
  const int wave  = tid >> 6;
  const int lane  = tid & 63;
  const int quad  = lane >> 4;
  const int col16 = lane & 15;
  const int row0  = by * 64;
  const int col0  = bx * 64;
  const int wr    = (wave >> 1) * 32;
  const int wc    = (wave & 1) * 32;

  const int srow = wave * 8 + (lane >> 3);
  const int scol = ((lane & 7) ^ ((lane >> 3) & 7)) * 8;
  const unsigned short* gA = A + (size_t)(row0 + srow) * D_ + scol;
  const unsigned short* gB = W + (size_t)(col0 + srow) * D_ + scol;

  f32x4 acc[2][2];
  #pragma unroll
  for (int mt = 0; mt < 2; ++mt)
    #pragma unroll
    for (int nt = 0; nt < 2; ++nt)
      #pragma unroll
      for (int r = 0; r < 4; ++r) acc[mt][nt][r] = 0.f;

  for (int k0 = 0; k0 < D_; k0 += 64) {
    __syncthreads();
    #pragma unroll
    for (int p = 0; p < 2; ++p) {
      gload_lds16(gA + (size_t)(p * 32) * D_ + k0, &As[(p * 32 + wave * 8) * 64]);
      gload_lds16(gB + (size_t)(p * 32) * D_ + k0, &Bs[(p * 32 + wave * 8) * 64]);
    }
    __syncthreads();

    #pragma unroll
    for (int h = 0; h < 2; ++h) {
      const int jo = ((h * 4 + quad) ^ (col16 & 7)) * 8;
      bf16x8 af[2], bfr[2];
      #pragma unroll
      for (int mt = 0; mt < 2; ++mt)
        af[mt] = *(const bf16x8*)&As[(wr + mt * 16 + col16) * 64 + jo];
      #pragma unroll
      for (int nt = 0; nt < 2; ++nt)
        bfr[nt] = *(const bf16x8*)&Bs[(wc + nt * 16 + col16) * 64 + jo];

      #pragma unroll
      for (int mt = 0; mt < 2; ++mt)
        #pragma unroll
        for (int nt = 0; nt < 2; ++nt)
          acc[mt][nt] = __builtin_amdgcn_mfma_f32_16x16x32_bf16(
              af[mt], bfr[nt], acc[mt][nt], 0, 0, 0);
    }
  }

  #pragma unroll
  for (int mt = 0; mt < 2; ++mt)
    #pragma unroll
    for (int r = 0; r < 4; ++r) {
      int row = row0 + wr + mt * 16 + quad * 4 + r;
      #pragma unroll
      for (int nt = 0; nt < 2; ++nt) {
        int col = col0 + wc + nt * 16 + col16;
        C[(size_t)row * D_ + col] = acc[mt][nt][r];
      }
    }
}

// ---------------------------------------------------------------------------
// Flash attention R6: NO K/V LDS staging — K/V are L2-resident (256 KB/head,
// XCD-local via bh block map), so each wave loads its MFMA fragments DIRECTLY
// from global (16B/lane, 64B row segments; 4 row-waves share tiles via L1).
// Main loop has ZERO barriers / ZERO DMA / zero inter-wave coupling:
//   load K-frags -> QK MFMA -> softmax (P via wave-private LDS) ->
//   load V-frags -> PV MFMA.
// 8 waves: rw = w&3 (16 q-rows), parity p = w>>2 processes keys g ≡ p (mod 2);
// fixed-max softmax -> parity partials combine by pure addition at the end.
// LDS = P only (18 KB).
// ---------------------------------------------------------------------------
__global__ __launch_bounds__(512)
void attn_mfma(const unsigned short* __restrict__ Q,
               const unsigned short* __restrict__ K,
               const unsigned short* __restrict__ Vt,
               unsigned short* __restrict__ O)
{
  const int f   = blockIdx.x;          // 0..1023
  const int qt  = 31 - (f >> 5);       // big q-tiles dispatched first
  const int bh  = f & 31;              // xcd = f&7 ~ bh&7 -> L2 locality
  const int b   = bh >> 4, h = bh & 15;

  const int tid  = threadIdx.x;
  const int w    = tid >> 6;
  const int lane = tid & 63;
  const int quad = lane >> 4;
  const int col  = lane & 15;
  const int rw   = w & 3;              // row-wave 0..3
  const int p    = w >> 2;             // key-parity group 0/1
  const int qlocal = rw * 16 + col;

  __shared__ __align__(16) unsigned short Pl[8][16][72]; // 18 KB, per-wave P

  const size_t qkbase = (size_t)b * S_ * D_ + (size_t)h * DK_;
  const size_t vtbase = (size_t)bh * DK_ * S_;

  const int qrow = qt * 64 + qlocal;
  bf16x8 qf[2];
  qf[0] = *(const bf16x8*)(Q + qkbase + (size_t)qrow * D_ + quad * 8);
  qf[1] = *(const bf16x8*)(Q + qkbase + (size_t)qrow * D_ + 32 + quad * 8);

  f32x4 Oacc[4];
  #pragma unroll
  for (int nb = 0; nb < 4; ++nb)
    #pragma unroll
    for (int r = 0; r < 4; ++r) Oacc[nb][r] = 0.f;
  float l_i = 0.f;

  const unsigned short* Kg = K + qkbase;    // row stride D_
  const unsigned short* Vg = Vt + vtbase;   // row stride S_
  unsigned short (*Plw)[72] = Pl[w];

  for (int g = p; g <= qt; g += 2) {
    const bool dg = (g == qt);

    // ---- QK^T: K fragments direct from global (L2/L1) ----
    f32x4 st[4];
    #pragma unroll
    for (int nb = 0; nb < 4; ++nb) {
      const unsigned short* kr =
          Kg + (size_t)(g * 64 + nb * 16 + col) * D_ + quad * 8;
      bf16x8 ka0 = *(const bf16x8*)kr;
      bf16x8 ka1 = *(const bf16x8*)(kr + 32);
      f32x4 a = {-24.f, -24.f, -24.f, -24.f};   // fixed-max bias
      a = __builtin_amdgcn_mfma_f32_16x16x32_bf16(ka0, qf[0], a, 0, 0, 0);
      a = __builtin_amdgcn_mfma_f32_16x16x32_bf16(ka1, qf[1], a, 0, 0, 0);
      st[nb] = a;
    }

    // ---- softmax (fixed-max, exp2 domain) ----
    if (dg) {
      #pragma unroll
      for (int nb = 0; nb < 4; ++nb)
        #pragma unroll
        for (int r = 0; r < 4; ++r)
          if (nb * 16 + quad * 4 + r > qlocal) st[nb][r] = -1e30f;
    }
    float rsum = 0.f;
    #pragma unroll
    for (int nb = 0; nb < 4; ++nb)
      #pragma unroll
      for (int r = 0; r < 4; ++r) {
        float pv = fast_exp2(st[nb][r]);
        st[nb][r] = pv;
        rsum += pv;
      }
    rsum += __shfl_xor(rsum, 16);
    rsum += __shfl_xor(rsum, 32);
    l_i += rsum;
    #pragma unroll
    for (int nb = 0; nb < 4; ++nb) {
      uint2 pk;
      pk.x = pack_trunc(st[nb][0], st[nb][1]);
      pk.y = pack_trunc(st[nb][2], st[nb][3]);
      *(uint2*)&Plw[col][nb * 16 + quad * 4] = pk;
    }
    bf16x8 pf0 = *(const bf16x8*)&Plw[col][quad * 8];
    bf16x8 pf1 = *(const bf16x8*)&Plw[col][32 + quad * 8];

    // ---- PV: V^T fragments direct from global (L2/L1) ----
    #pragma unroll
    for (int nb = 0; nb < 4; ++nb) {
      const unsigned short* vr =
          Vg + (size_t)(nb * 16 + col) * S_ + g * 64 + quad * 8;
      bf16x8 va0 = *(const bf16x8*)vr;
      bf16x8 va1 = *(const bf16x8*)(vr + 32);
      Oacc[nb] = __builtin_amdgcn_mfma_f32_16x16x32_bf16(va0, pf0, Oacc[nb], 0, 0, 0);
      Oacc[nb] = __builtin_amdgcn_mfma_f32_16x16x32_bf16(va1, pf1, Oacc[nb], 0, 0, 0);
    }
  }

  // ---- combine parity partials (pure add: fixed-max, no rescale) ----
  __syncthreads();                                    // all waves done; LDS reusable
  float* sc = (float*)&Pl[0][0][0];                   // 18 KB scratch
  if (p == 1) {
    float* d0 = sc + ((size_t)(rw * 64 + lane)) * 18;
    #pragma unroll
    for (int nb = 0; nb < 4; ++nb)
      #pragma unroll
      for (int r = 0; r < 4; ++r) d0[nb * 4 + r] = Oacc[nb][r];
    d0[16] = l_i;
  }
  __syncthreads();
  if (p == 0) {
    const float* s0 = sc + ((size_t)(rw * 64 + lane)) * 18;
    const float inv = 1.0f / (l_i + s0[16]);
    #pragma unroll
    for (int nb = 0; nb < 4; ++nb) {
      int d = nb * 16 + quad * 4;
      ushort4 oa;
      oa.x = f2bf((Oacc[nb][0] + s0[nb * 4 + 0]) * inv);
      oa.y = f2bf((Oacc[nb][1] + s0[nb * 4 + 1]) * inv);
      oa.z = f2bf((Oacc[nb][2] + s0[nb * 4 + 2]) * inv);
      oa.w = f2bf((Oacc[nb][3] + s0[nb * 4 + 3]) * inv);
      *(ushort4*)(O + (size_t)b * S_ * D_ + (size_t)qrow * D_ + h * DK_ + d) = oa;
    }
  }
}

// ---------------------------------------------------------------------------
extern "C" void kernel_launch(void* const* d_in, const int* in_sizes, int n_in,
                              void* d_out, int out_size, void* d_ws, size_t ws_size,
                              hipStream_t stream)
{
  const float* x  = (const float*)d_in[0];
  const float* Wq = (const float*)d_in[1];
  const float* Wk = (const float*)d_in[2];
  const float* Wv = (const float*)d_in[3];
  const float* Wo = (const float*)d_in[4];
  const int*   tp = (const int*)d_in[5];
  float* out = (float*)d_out;

  const size_t NTOK = (size_t)B_ * S_ * D_;     // 4,194,304 elements
  const size_t NW   = (size_t)D_ * D_;          // 1,048,576
  unsigned short* qh  = (unsigned short*)d_ws;  // bf16 [B,S,D]
  unsigned short* kh  = qh + NTOK;
  unsigned short* vt  = kh + NTOK;              // bf16 [B*H, 64, S]
  unsigned short* xb  = vt + NTOK;              // bf16 [B,S,D]; reused as ab
  unsigned short* wqb = xb + NTOK;
  unsigned short* wkb = wqb + NW;
  unsigned short* wvb = wkb + NW;
  unsigned short* wob = wvb + NW;
  unsigned short* ab  = xb;                     // alias: xb dead after QKV gemm

  // fp32 -> bf16 casts
  cast5_bf16<<<dim3(4096), 256, 0, stream>>>(
      x, Wq, Wk, Wv, Wo, xb, wqb, wkb, wvb, wob);

  // fused QKV projection + RoPE + Q-scale + direct-V^T, 64x128 tiles
  gemm_qkv<<<dim3(8, 64, 3), 256, 0, stream>>>(
      xb, wqb, wkb, wvb, qh, kh, vt, tp);

  // 8-wave barrier-free flash attention (K/V direct from L2) -> bf16 ab
  attn_mfma<<<dim3(32 * 32), 512, 0, stream>>>(qh, kh, vt, ab);

  // output projection, 64x64 tiles -> fp32 out
  gemm_wo<<<dim3(16, 64), 256, 0, stream>>>(ab, wob, out);
}

// Round 7
// 171.361 us; speedup vs baseline: 1.5313x; 1.5313x over previous
//
#include <hip/hip_runtime.h>
#include <hip/hip_bf16.h>
#include <math.h>

#define B_  2
#define S_  2048
#define H_  16
#define D_  1024
#define DK_ 64

typedef __attribute__((ext_vector_type(8))) short bf16x8;   // 8 bf16 = 4 VGPRs
typedef __attribute__((ext_vector_type(8))) unsigned short ushort8v;
typedef __attribute__((ext_vector_type(4))) float f32x4;

__device__ __forceinline__ unsigned short f2bf(float f) {
  unsigned u = __float_as_uint(f);
  unsigned r = (u + 0x7FFFu + ((u >> 16) & 1u)) >> 16;   // RNE
  return (unsigned short)r;
}
// truncation pack: two fp32 -> packed bf16x2 (P>=0; relative err ~2^-8, OK)
__device__ __forceinline__ unsigned pack_trunc(float lo, float hi) {
  return (__float_as_uint(lo) >> 16) | (__float_as_uint(hi) & 0xffff0000u);
}
__device__ __forceinline__ float fast_exp2(float x) {
#if __has_builtin(__builtin_amdgcn_exp2f)
  return __builtin_amdgcn_exp2f(x);
#else
  return __expf(x * 0.69314718056f);
#endif
}
// async global->LDS, 16B/lane. LDS dest = wave-uniform base + lane*16.
__device__ __forceinline__ void gload_lds16(const unsigned short* g,
                                            unsigned short* l) {
  __builtin_amdgcn_global_load_lds(
      (const __attribute__((address_space(1))) unsigned int*)(const void*)g,
      (__attribute__((address_space(3))) unsigned int*)(void*)l, 16, 0, 0);
}

// ---------------------------------------------------------------------------
// Cast fp32 -> bf16 for x (2048 blocks) + 4 weights (512 blocks each).
// ---------------------------------------------------------------------------
__global__ __launch_bounds__(256)
void cast5_bf16(const float* __restrict__ x,  const float* __restrict__ wq,
                const float* __restrict__ wk, const float* __restrict__ wv,
                const float* __restrict__ wo,
                unsigned short* __restrict__ xb,  unsigned short* __restrict__ wqb,
                unsigned short* __restrict__ wkb, unsigned short* __restrict__ wvb,
                unsigned short* __restrict__ wob)
{
  const int idx = blockIdx.x;
  const float* s; unsigned short* d; int lblk;
  if (idx < 2048) { s = x; d = xb; lblk = idx; }
  else {
    int t = idx - 2048;
    int w = t >> 9;          // 0..3
    lblk  = t & 511;
    s = (w == 0) ? wq  : (w == 1) ? wk  : (w == 2) ? wv  : wo;
    d = (w == 0) ? wqb : (w == 1) ? wkb : (w == 2) ? wvb : wob;
  }
  size_t i0 = ((size_t)lblk * 256 + threadIdx.x) * 8;
  float4 v0 = *(const float4*)(s + i0);
  float4 v1 = *(const float4*)(s + i0 + 4);
  ushort8v o;
  o[0] = f2bf(v0.x); o[1] = f2bf(v0.y); o[2] = f2bf(v0.z); o[3] = f2bf(v0.w);
  o[4] = f2bf(v1.x); o[5] = f2bf(v1.y); o[6] = f2bf(v1.z); o[7] = f2bf(v1.w);
  *(ushort8v*)(d + i0) = o;
}

// ---------------------------------------------------------------------------
// Fused QKV projection GEMM. R7: 64x64 tiles -> 1024 blocks per z (3072
// total, 12/CU queued), 16.25 KB LDS, launch_bounds(256,8) to force
// VGPR<=64 -> 8 waves/SIMD residency (the only lever that has moved perf
// this session). Single-buffered syncthreads staging (R2-proven; dbuf was
// neutral in R4). Mod-8 XOR swizzle rows.
// blockIdx.z: 0=Q, 1=K, 2=V (operand swap -> V^T).
// XCD-chunked map: blocks with flat%8==c share 8 row-panels -> <=3MB/XCD L2.
// ---------------------------------------------------------------------------
__global__ __launch_bounds__(256, 8)
void gemm_qkv(const unsigned short* __restrict__ A0,
              const unsigned short* __restrict__ W0,
              const unsigned short* __restrict__ W1,
              const unsigned short* __restrict__ W2,
              unsigned short* __restrict__ qh,
              unsigned short* __restrict__ kh,
              unsigned short* __restrict__ vt,
              const int* __restrict__ tp)
{
  const int z    = blockIdx.z;
  const int flat = blockIdx.y * 16 + blockIdx.x;  // 0..1023
  const int xcd  = flat & 7;
  const int u    = flat >> 3;                     // 0..127
  const int byp  = xcd * 8 + (u & 7);             // 0..63 (token tile)
  const int bxp  = u >> 3;                        // 0..15 (channel tile)

  const int row0 = (z == 2) ? bxp * 64 : byp * 64;
  const int col0 = (z == 2) ? byp * 64 : bxp * 64;
  const unsigned short* Aptr = (z == 2) ? W2 : A0;
  const unsigned short* Bptr = (z == 0) ? W0 : (z == 1) ? W1 : A0;

  __shared__ unsigned short As[64 * 64];    // 8 KB
  __shared__ unsigned short Bs[64 * 64];    // 8 KB
  __shared__ int tps[64];

  const int tid   = threadIdx.x;
  const int wave  = tid >> 6;
  const int lane  = tid & 63;
  const int quad  = lane >> 4;
  const int col16 = lane & 15;
  const int wr    = (wave >> 1) * 32;
  const int wc    = (wave & 1) * 32;

  if (z < 2 && tid < 64) tps[tid] = tp[row0 + tid];

  const int srow = wave * 8 + (lane >> 3);
  const int scol = ((lane & 7) ^ ((lane >> 3) & 7)) * 8;
  const unsigned short* gA = Aptr + (size_t)(row0 + srow) * D_ + scol;
  const unsigned short* gB = Bptr + (size_t)(col0 + srow) * D_ + scol;

  f32x4 acc[2][2];
  #pragma unroll
  for (int mt = 0; mt < 2; ++mt)
    #pragma unroll
    for (int nt = 0; nt < 2; ++nt)
      #pragma unroll
      for (int r = 0; r < 4; ++r) acc[mt][nt][r] = 0.f;

  for (int k0 = 0; k0 < D_; k0 += 64) {
    __syncthreads();
    #pragma unroll
    for (int p = 0; p < 2; ++p) {
      gload_lds16(gA + (size_t)(p * 32) * D_ + k0, &As[(p * 32 + wave * 8) * 64]);
      gload_lds16(gB + (size_t)(p * 32) * D_ + k0, &Bs[(p * 32 + wave * 8) * 64]);
    }
    __syncthreads();

    #pragma unroll
    for (int h = 0; h < 2; ++h) {
      const int jo = ((h * 4 + quad) ^ (col16 & 7)) * 8;
      bf16x8 af[2], bfr[2];
      #pragma unroll
      for (int mt = 0; mt < 2; ++mt)
        af[mt] = *(const bf16x8*)&As[(wr + mt * 16 + col16) * 64 + jo];
      #pragma unroll
      for (int nt = 0; nt < 2; ++nt)
        bfr[nt] = *(const bf16x8*)&Bs[(wc + nt * 16 + col16) * 64 + jo];

      #pragma unroll
      for (int mt = 0; mt < 2; ++mt)
        #pragma unroll
        for (int nt = 0; nt < 2; ++nt)
          acc[mt][nt] = __builtin_amdgcn_mfma_f32_16x16x32_bf16(
              af[mt], bfr[nt], acc[mt][nt], 0, 0, 0);
    }
  }

  if (z == 2) {
    // C = V^T: row = channel c, col = token t; lanes are consecutive tokens.
    #pragma unroll
    for (int mt = 0; mt < 2; ++mt)
      #pragma unroll
      for (int r = 0; r < 4; ++r) {
        int c = row0 + wr + mt * 16 + quad * 4 + r;   // channel
        int h = c >> 6, d = c & 63;
        #pragma unroll
        for (int nt = 0; nt < 2; ++nt) {
          int t  = col0 + wc + nt * 16 + col16;       // token
          int bb = t >> 11, sl = t & (S_ - 1);
          vt[((size_t)((bb << 4) + h) * DK_ + d) * S_ + sl] =
              f2bf(acc[mt][nt][r]);
        }
      }
  } else {
    unsigned short* C = z ? kh : qh;
    const float qs = z ? 1.0f : 0.1803368801111204f;  // 0.125*log2(e) for Q
    const float sgn = (col16 & 1) ? 1.f : -1.f;       // even lane: re = v*c - o*s
    float freqr[2];
    #pragma unroll
    for (int nt = 0; nt < 2; ++nt) {
      int i = ((wc + nt * 16 + col16) & 63) >> 1;
      freqr[nt] = exp2f(-0.4152410118f * (float)i);   // 10000^(-2i/64)
    }
    #pragma unroll
    for (int mt = 0; mt < 2; ++mt)
      #pragma unroll
      for (int r = 0; r < 4; ++r) {
        int rl  = wr + mt * 16 + quad * 4 + r;
        int row = row0 + rl;
        float p = (float)tps[rl];
        #pragma unroll
        for (int nt = 0; nt < 2; ++nt) {
          int col = col0 + wc + nt * 16 + col16;
          float ang = p * freqr[nt];
          float sn = __sinf(ang), cs = __cosf(ang);
          float val = acc[mt][nt][r];
          float oth = __shfl_xor(val, 1);
          C[(size_t)row * D_ + col] = f2bf((val * cs + oth * sgn * sn) * qs);
        }
      }
  }
}

// ---------------------------------------------------------------------------
// Wo projection GEMM. 64x64 tiles -> 1024 blocks, 16 KB LDS, bounds(256,8).
// (unchanged from R5)
// ---------------------------------------------------------------------------
__global__ __launch_bounds__(256, 8)
void gemm_wo(const unsigned short* __restrict__ A,
             const unsigned short* __restrict__ W,
             float* __restrict__ C)
{
  __shared__ unsigned short As[64 * 64];    // 8 KB
  __shared__ unsigned short Bs[64 * 64];    // 8 KB

  const int flat = blockIdx.y * 16 + blockIdx.x;  // 0..1023
  const int xcd  = flat & 7;
  const int u    = flat >> 3;                     // 0..127
  const int by   = xcd * 8 + (u & 7);             // 0..63
  const int bx   = u >> 3;                        // 0..15

  const int tid   = threadIdx.x;
  const int wave  = tid >> 6;
  const int lane  = tid & 63;
  const int quad  = lane >> 4;
  const int col16 = lane & 15;
  const int row0  = by * 64;
  const int col0  = bx * 64;
  const int wr    = (wave >> 1) * 32;
  const int wc    = (wave & 1) * 32;

  const int srow = wave * 8 + (lane >> 3);
  const int scol = ((lane & 7) ^ ((lane >> 3) & 7)) * 8;
  const unsigned short* gA = A + (size_t)(row0 + srow) * D_ + scol;
  const unsigned short* gB = W + (size_t)(col0 + srow) * D_ + scol;

  f32x4 acc[2][2];
  #pragma unroll
  for (int mt = 0; mt < 2; ++mt)
    #pragma unroll
    for (int nt = 0; nt < 2; ++nt)
      #pragma unroll
      for (int r = 0; r < 4; ++r) acc[mt][nt][r] = 0.f;

  for (int k0 = 0; k0 < D_; k0 += 64) {
    __syncthreads();
    #pragma unroll
    for (int p = 0; p < 2; ++p) {
      gload_lds16(gA + (size_t)(p * 32) * D_ + k0, &As[(p * 32 + wave * 8) * 64]);
      gload_lds16(gB + (size_t)(p * 32) * D_ + k0, &Bs[(p * 32 + wave * 8) * 64]);
    }
    __syncthreads();

    #pragma unroll
    for (int h = 0; h < 2; ++h) {
      const int jo = ((h * 4 + quad) ^ (col16 & 7)) * 8;
      bf16x8 af[2], bfr[2];
      #pragma unroll
      for (int mt = 0; mt < 2; ++mt)
        af[mt] = *(const bf16x8*)&As[(wr + mt * 16 + col16) * 64 + jo];
      #pragma unroll
      for (int nt = 0; nt < 2; ++nt)
        bfr[nt] = *(const bf16x8*)&Bs[(wc + nt * 16 + col16) * 64 + jo];

      #pragma unroll
      for (int mt = 0; mt < 2; ++mt)
        #pragma unroll
        for (int nt = 0; nt < 2; ++nt)
          acc[mt][nt] = __builtin_amdgcn_mfma_f32_16x16x32_bf16(
              af[mt], bfr[nt], acc[mt][nt], 0, 0, 0);
    }
  }

  #pragma unroll
  for (int mt = 0; mt < 2; ++mt)
    #pragma unroll
    for (int r = 0; r < 4; ++r) {
      int row = row0 + wr + mt * 16 + quad * 4 + r;
      #pragma unroll
      for (int nt = 0; nt < 2; ++nt) {
        int col = col0 + wc + nt * 16 + col16;
        C[(size_t)row * D_ + col] = acc[mt][nt][r];
      }
    }
}

// ---------------------------------------------------------------------------
// Flash attention, 8-wave key-parity structure with LDS staging (R5 exact
// restore — R6's staging-free variant was 3x slower: scattered 64B fragment
// loads serialize on L2 latency; coalesced global_load_lds staging is
// essential). launch_bounds(512,8) forces VGPR<=64 -> 3 blocks/CU (LDS cap).
// ---------------------------------------------------------------------------
__global__ __launch_bounds__(512, 8)
void attn_mfma(const unsigned short* __restrict__ Q,
               const unsigned short* __restrict__ K,
               const unsigned short* __restrict__ Vt,
               unsigned short* __restrict__ O)
{
  const int f   = blockIdx.x;          // 0..1023
  const int qt  = 31 - (f >> 5);       // big q-tiles dispatched first
  const int bh  = f & 31;              // xcd = f&7 ~ bh&7 -> L2 locality
  const int b   = bh >> 4, h = bh & 15;

  const int tid  = threadIdx.x;
  const int w    = tid >> 6;
  const int lane = tid & 63;
  const int quad = lane >> 4;
  const int col  = lane & 15;
  const int rw   = w & 3;              // row-wave 0..3
  const int p    = w >> 2;             // key-parity group 0/1
  const int qlocal = rw * 16 + col;

  __shared__ unsigned short Ks[2 * 4096];               // 2 x 64-key slot, 16 KB
  __shared__ unsigned short Vs[2 * 4096];               // 16 KB
  __shared__ __align__(16) unsigned short Pl[8][16][72]; // 18 KB, per-wave P

  const size_t qkbase = (size_t)b * S_ * D_ + (size_t)h * DK_;
  const size_t vtbase = (size_t)bh * DK_ * S_;

  const int qrow = qt * 64 + qlocal;
  bf16x8 qf[2];
  qf[0] = *(const bf16x8*)(Q + qkbase + (size_t)qrow * D_ + quad * 8);
  qf[1] = *(const bf16x8*)(Q + qkbase + (size_t)qrow * D_ + 32 + quad * 8);

  // staging: wave covers 16 rows (2 gloads x 8 rows) of its own slot p.
  const int lr8 = lane >> 3;                       // 0..7 row within 8
  const int sj  = ((lane & 7) ^ (lr8 & 7)) * 8;    // swizzled source octet

  auto stageK = [&](int g) {
    const int gc = (g > qt) ? qt : g;
    const unsigned short* s =
        K + qkbase + (size_t)(gc * 64 + rw * 16 + lr8) * D_ + sj;
    #pragma unroll
    for (int pp = 0; pp < 2; ++pp)
      gload_lds16(s + (size_t)(pp * 8) * D_, &Ks[p * 4096 + (rw * 16 + pp * 8) * 64]);
  };
  auto stageV = [&](int g) {
    const int gc = (g > qt) ? qt : g;
    const unsigned short* s =
        Vt + vtbase + (size_t)(rw * 16 + lr8) * S_ + gc * 64 + sj;
    #pragma unroll
    for (int pp = 0; pp < 2; ++pp)
      gload_lds16(s + (size_t)(pp * 8) * S_, &Vs[p * 4096 + (rw * 16 + pp * 8) * 64]);
  };

  f32x4 Oacc[4];
  #pragma unroll
  for (int nb = 0; nb < 4; ++nb)
    #pragma unroll
    for (int r = 0; r < 4; ++r) Oacc[nb][r] = 0.f;
  float l_i = 0.f;

  const int M  = (qt >> 1) + 1;        // pair-iterations
  const int jx = quad ^ (col & 7);
  const unsigned short* KsH = Ks + p * 4096;
  const unsigned short* VsH = Vs + p * 4096;
  unsigned short (*Plw)[72] = Pl[w];

  stageK(p);
  stageV(p);
  asm volatile("s_waitcnt vmcnt(0)" ::: "memory");
  __builtin_amdgcn_s_barrier();
  __builtin_amdgcn_sched_barrier(0);

  for (int m = 0; m < M; ++m) {
    const int g    = 2 * m + p;
    const bool act = (g <= qt);
    const bool dg  = (g == qt);

    f32x4 st[4];
    if (act) {                       // QK^T from own K slot
      __builtin_amdgcn_s_setprio(1);
      #pragma unroll
      for (int nb = 0; nb < 4; ++nb) {
        const int s0 = (nb * 16 + col) * 8 + jx;
        bf16x8 ka0 = *(const bf16x8*)(KsH + s0 * 8);
        bf16x8 ka1 = *(const bf16x8*)(KsH + (s0 ^ 4) * 8);
        f32x4 a = {-24.f, -24.f, -24.f, -24.f};   // fixed-max bias
        a = __builtin_amdgcn_mfma_f32_16x16x32_bf16(ka0, qf[0], a, 0, 0, 0);
        a = __builtin_amdgcn_mfma_f32_16x16x32_bf16(ka1, qf[1], a, 0, 0, 0);
        st[nb] = a;
      }
      __builtin_amdgcn_s_setprio(0);
    }
    __builtin_amdgcn_sched_barrier(0);
    __builtin_amdgcn_s_barrier();            // all QK K-reads complete
    __builtin_amdgcn_sched_barrier(0);

    stageK(2 * m + 2 + p);                   // overwrite own K slot (next pair)

    if (act) {                               // softmax (fixed-max, exp2 domain)
      if (dg) {
        #pragma unroll
        for (int nb = 0; nb < 4; ++nb)
          #pragma unroll
          for (int r = 0; r < 4; ++r)
            if (nb * 16 + quad * 4 + r > qlocal) st[nb][r] = -1e30f;
      }
      float rsum = 0.f;
      #pragma unroll
      for (int nb = 0; nb < 4; ++nb)
        #pragma unroll
        for (int r = 0; r < 4; ++r) {
          float pv = fast_exp2(st[nb][r]);
          st[nb][r] = pv;
          rsum += pv;
        }
      rsum += __shfl_xor(rsum, 16);
      rsum += __shfl_xor(rsum, 32);
      l_i += rsum;
      #pragma unroll
      for (int nb = 0; nb < 4; ++nb) {
        uint2 pk;
        pk.x = pack_trunc(st[nb][0], st[nb][1]);
        pk.y = pack_trunc(st[nb][2], st[nb][3]);
        *(uint2*)&Plw[col][nb * 16 + quad * 4] = pk;
      }
    }

    asm volatile("s_waitcnt vmcnt(2)" ::: "memory");  // own V(pair m) landed
    __builtin_amdgcn_sched_barrier(0);
    __builtin_amdgcn_s_barrier();            // everyone's V landed
    __builtin_amdgcn_sched_barrier(0);

    if (act) {                               // PV from own V slot
      bf16x8 pf0 = *(const bf16x8*)&Plw[col][quad * 8];
      bf16x8 pf1 = *(const bf16x8*)&Plw[col][32 + quad * 8];
      __builtin_amdgcn_s_setprio(1);
      #pragma unroll
      for (int nb = 0; nb < 4; ++nb) {
        const int s0 = (nb * 16 + col) * 8 + jx;
        bf16x8 va0 = *(const bf16x8*)(VsH + s0 * 8);
        bf16x8 va1 = *(const bf16x8*)(VsH + (s0 ^ 4) * 8);
        Oacc[nb] = __builtin_amdgcn_mfma_f32_16x16x32_bf16(va0, pf0, Oacc[nb], 0, 0, 0);
        Oacc[nb] = __builtin_amdgcn_mfma_f32_16x16x32_bf16(va1, pf1, Oacc[nb], 0, 0, 0);
      }
      __builtin_amdgcn_s_setprio(0);
    }
    __builtin_amdgcn_sched_barrier(0);
    __builtin_amdgcn_s_barrier();            // all V-reads complete
    __builtin_amdgcn_sched_barrier(0);

    stageV(2 * m + 2 + p);                   // overwrite own V slot (next pair)
    asm volatile("s_waitcnt vmcnt(2)" ::: "memory");  // own K(next) landed
    __builtin_amdgcn_sched_barrier(0);
    __builtin_amdgcn_s_barrier();            // everyone's K landed
    __builtin_amdgcn_sched_barrier(0);
  }

  // ---- combine parity partials (pure add: fixed-max, no rescale) ----
  asm volatile("s_waitcnt vmcnt(0)" ::: "memory");    // tail DMA landed
  __syncthreads();                                    // LDS reusable
  float* sc = (float*)&Pl[0][0][0];                   // 18 KB scratch
  if (p == 1) {
    float* d0 = sc + ((size_t)(rw * 64 + lane)) * 18;
    #pragma unroll
    for (int nb = 0; nb < 4; ++nb)
      #pragma unroll
      for (int r = 0; r < 4; ++r) d0[nb * 4 + r] = Oacc[nb][r];
    d0[16] = l_i;
  }
  __syncthreads();
  if (p == 0) {
    const float* s0 = sc + ((size_t)(rw * 64 + lane)) * 18;
    const float inv = 1.0f / (l_i + s0[16]);
    #pragma unroll
    for (int nb = 0; nb < 4; ++nb) {
      int d = nb * 16 + quad * 4;
      ushort4 oa;
      oa.x = f2bf((Oacc[nb][0] + s0[nb * 4 + 0]) * inv);
      oa.y = f2bf((Oacc[nb][1] + s0[nb * 4 + 1]) * inv);
      oa.z = f2bf((Oacc[nb][2] + s0[nb * 4 + 2]) * inv);
      oa.w = f2bf((Oacc[nb][3] + s0[nb * 4 + 3]) * inv);
      *(ushort4*)(O + (size_t)b * S_ * D_ + (size_t)qrow * D_ + h * DK_ + d) = oa;
    }
  }
}

// ---------------------------------------------------------------------------
extern "C" void kernel_launch(void* const* d_in, const int* in_sizes, int n_in,
                              void* d_out, int out_size, void* d_ws, size_t ws_size,
                              hipStream_t stream)
{
  const float* x  = (const float*)d_in[0];
  const float* Wq = (const float*)d_in[1];
  const float* Wk = (const float*)d_in[2];
  const float* Wv = (const float*)d_in[3];
  const float* Wo = (const float*)d_in[4];
  const int*   tp = (const int*)d_in[5];
  float* out = (float*)d_out;

  const size_t NTOK = (size_t)B_ * S_ * D_;     // 4,194,304 elements
  const size_t NW   = (size_t)D_ * D_;          // 1,048,576
  unsigned short* qh  = (unsigned short*)d_ws;  // bf16 [B,S,D]
  unsigned short* kh  = qh + NTOK;
  unsigned short* vt  = kh + NTOK;              // bf16 [B*H, 64, S]
  unsigned short* xb  = vt + NTOK;              // bf16 [B,S,D]; reused as ab
  unsigned short* wqb = xb + NTOK;
  unsigned short* wkb = wqb + NW;
  unsigned short* wvb = wkb + NW;
  unsigned short* wob = wvb + NW;
  unsigned short* ab  = xb;                     // alias: xb dead after QKV gemm

  // fp32 -> bf16 casts
  cast5_bf16<<<dim3(4096), 256, 0, stream>>>(
      x, Wq, Wk, Wv, Wo, xb, wqb, wkb, wvb, wob);

  // fused QKV projection + RoPE + Q-scale + direct-V^T, 64x64 tiles
  gemm_qkv<<<dim3(16, 64, 3), 256, 0, stream>>>(
      xb, wqb, wkb, wvb, qh, kh, vt, tp);

  // 8-wave key-parity flash attention (fixed-max softmax) -> bf16 ab
  attn_mfma<<<dim3(32 * 32), 512, 0, stream>>>(qh, kh, vt, ab);

  // output projection, 64x64 tiles -> fp32 out
  gemm_wo<<<dim3(16, 64), 256, 0, stream>>>(ab, wob, out);
}

// Round 8
// 171.149 us; speedup vs baseline: 1.5332x; 1.0012x over previous
//
#include <hip/hip_runtime.h>
#include <hip/hip_bf16.h>
#include <math.h>

#define B_  2
#define S_  2048
#define H_  16
#define D_  1024
#define DK_ 64

typedef __attribute__((ext_vector_type(8))) short bf16x8;   // 8 bf16 = 4 VGPRs
typedef __attribute__((ext_vector_type(8))) unsigned short ushort8v;
typedef __attribute__((ext_vector_type(4))) float f32x4;

__device__ __forceinline__ unsigned short f2bf(float f) {
  unsigned u = __float_as_uint(f);
  unsigned r = (u + 0x7FFFu + ((u >> 16) & 1u)) >> 16;   // RNE
  return (unsigned short)r;
}
// truncation pack: two fp32 -> packed bf16x2 (P>=0; relative err ~2^-8, OK)
__device__ __forceinline__ unsigned pack_trunc(float lo, float hi) {
  return (__float_as_uint(lo) >> 16) | (__float_as_uint(hi) & 0xffff0000u);
}
__device__ __forceinline__ float fast_exp2(float x) {
#if __has_builtin(__builtin_amdgcn_exp2f)
  return __builtin_amdgcn_exp2f(x);
#else
  return __expf(x * 0.69314718056f);
#endif
}
// async global->LDS, 16B/lane. LDS dest = wave-uniform base + lane*16.
__device__ __forceinline__ void gload_lds16(const unsigned short* g,
                                            unsigned short* l) {
  __builtin_amdgcn_global_load_lds(
      (const __attribute__((address_space(1))) unsigned int*)(const void*)g,
      (__attribute__((address_space(3))) unsigned int*)(void*)l, 16, 0, 0);
}

// ---------------------------------------------------------------------------
// Cast fp32 -> bf16 for x (2048 blocks) + 4 weights (512 blocks each).
// ---------------------------------------------------------------------------
__global__ __launch_bounds__(256)
void cast5_bf16(const float* __restrict__ x,  const float* __restrict__ wq,
                const float* __restrict__ wk, const float* __restrict__ wv,
                const float* __restrict__ wo,
                unsigned short* __restrict__ xb,  unsigned short* __restrict__ wqb,
                unsigned short* __restrict__ wkb, unsigned short* __restrict__ wvb,
                unsigned short* __restrict__ wob)
{
  const int idx = blockIdx.x;
  const float* s; unsigned short* d; int lblk;
  if (idx < 2048) { s = x; d = xb; lblk = idx; }
  else {
    int t = idx - 2048;
    int w = t >> 9;          // 0..3
    lblk  = t & 511;
    s = (w == 0) ? wq  : (w == 1) ? wk  : (w == 2) ? wv  : wo;
    d = (w == 0) ? wqb : (w == 1) ? wkb : (w == 2) ? wvb : wob;
  }
  size_t i0 = ((size_t)lblk * 256 + threadIdx.x) * 8;
  float4 v0 = *(const float4*)(s + i0);
  float4 v1 = *(const float4*)(s + i0 + 4);
  ushort8v o;
  o[0] = f2bf(v0.x); o[1] = f2bf(v0.y); o[2] = f2bf(v0.z); o[3] = f2bf(v0.w);
  o[4] = f2bf(v1.x); o[5] = f2bf(v1.y); o[6] = f2bf(v1.z); o[7] = f2bf(v1.w);
  *(ushort8v*)(d + i0) = o;
}

// ---------------------------------------------------------------------------
// Fused QKV projection GEMM. 64(M)x128(N) tiles -> 512 blocks per z,
// 24 KB single-buffered LDS (R5-proven config, best measured).
// blockIdx.z: 0=Q, 1=K, 2=V (operand swap -> V^T). Mod-8 XOR swizzle rows.
// ---------------------------------------------------------------------------
__global__ __launch_bounds__(256)
void gemm_qkv(const unsigned short* __restrict__ A0,
              const unsigned short* __restrict__ W0,
              const unsigned short* __restrict__ W1,
              const unsigned short* __restrict__ W2,
              unsigned short* __restrict__ qh,
              unsigned short* __restrict__ kh,
              unsigned short* __restrict__ vt,
              const int* __restrict__ tp)
{
  const int z    = blockIdx.z;
  const int flat = blockIdx.y * 8 + blockIdx.x;   // 0..511
  const int xcd  = flat & 7;
  const int u    = flat >> 3;                     // 0..63

  int row0, col0;
  if (z < 2) {
    row0 = (xcd * 8 + (u & 7)) * 64;
    col0 = (u >> 3) * 128;
  } else {
    int tc = xcd * 4 + (u & 3);
    int cr = u >> 2;
    row0 = cr * 64;
    col0 = tc * 128;
  }
  const unsigned short* Aptr = (z == 2) ? W2 : A0;
  const unsigned short* Bptr = (z == 0) ? W0 : (z == 1) ? W1 : A0;

  __shared__ unsigned short As[64 * 64];    // 8 KB
  __shared__ unsigned short Bs[128 * 64];   // 16 KB
  __shared__ int tps[64];

  const int tid   = threadIdx.x;
  const int wave  = tid >> 6;
  const int lane  = tid & 63;
  const int quad  = lane >> 4;
  const int col16 = lane & 15;
  const int wr    = (wave >> 1) * 32;
  const int wc    = (wave & 1) * 64;

  if (z < 2 && tid < 64) tps[tid] = tp[row0 + tid];

  const int srow = wave * 8 + (lane >> 3);
  const int scol = ((lane & 7) ^ ((lane >> 3) & 7)) * 8;
  const unsigned short* gA = Aptr + (size_t)(row0 + srow) * D_ + scol;
  const unsigned short* gB = Bptr + (size_t)(col0 + srow) * D_ + scol;

  f32x4 acc[2][4];
  #pragma unroll
  for (int mt = 0; mt < 2; ++mt)
    #pragma unroll
    for (int nt = 0; nt < 4; ++nt)
      #pragma unroll
      for (int r = 0; r < 4; ++r) acc[mt][nt][r] = 0.f;

  for (int k0 = 0; k0 < D_; k0 += 64) {
    __syncthreads();
    #pragma unroll
    for (int p = 0; p < 2; ++p)
      gload_lds16(gA + (size_t)(p * 32) * D_ + k0, &As[(p * 32 + wave * 8) * 64]);
    #pragma unroll
    for (int p = 0; p < 4; ++p)
      gload_lds16(gB + (size_t)(p * 32) * D_ + k0, &Bs[(p * 32 + wave * 8) * 64]);
    __syncthreads();

    #pragma unroll
    for (int h = 0; h < 2; ++h) {
      const int jo = ((h * 4 + quad) ^ (col16 & 7)) * 8;
      bf16x8 af[2], bfr[4];
      #pragma unroll
      for (int mt = 0; mt < 2; ++mt)
        af[mt] = *(const bf16x8*)&As[(wr + mt * 16 + col16) * 64 + jo];
      #pragma unroll
      for (int nt = 0; nt < 4; ++nt)
        bfr[nt] = *(const bf16x8*)&Bs[(wc + nt * 16 + col16) * 64 + jo];

      #pragma unroll
      for (int mt = 0; mt < 2; ++mt)
        #pragma unroll
        for (int nt = 0; nt < 4; ++nt)
          acc[mt][nt] = __builtin_amdgcn_mfma_f32_16x16x32_bf16(
              af[mt], bfr[nt], acc[mt][nt], 0, 0, 0);
    }
  }

  if (z == 2) {
    #pragma unroll
    for (int mt = 0; mt < 2; ++mt)
      #pragma unroll
      for (int r = 0; r < 4; ++r) {
        int c = row0 + wr + mt * 16 + quad * 4 + r;   // channel
        int h = c >> 6, d = c & 63;
        #pragma unroll
        for (int nt = 0; nt < 4; ++nt) {
          int t  = col0 + wc + nt * 16 + col16;       // token
          int bb = t >> 11, sl = t & (S_ - 1);
          vt[((size_t)((bb << 4) + h) * DK_ + d) * S_ + sl] =
              f2bf(acc[mt][nt][r]);
        }
      }
  } else {
    unsigned short* C = z ? kh : qh;
    const float qs = z ? 1.0f : 0.1803368801111204f;  // 0.125*log2(e) for Q
    const float sgn = (col16 & 1) ? 1.f : -1.f;       // even lane: re = v*c - o*s
    float freqr[4];
    #pragma unroll
    for (int nt = 0; nt < 4; ++nt) {
      int i = ((wc + nt * 16 + col16) & 63) >> 1;
      freqr[nt] = exp2f(-0.4152410118f * (float)i);   // 10000^(-2i/64)
    }
    #pragma unroll
    for (int mt = 0; mt < 2; ++mt)
      #pragma unroll
      for (int r = 0; r < 4; ++r) {
        int rl  = wr + mt * 16 + quad * 4 + r;
        int row = row0 + rl;
        float p = (float)tps[rl];
        #pragma unroll
        for (int nt = 0; nt < 4; ++nt) {
          int col = col0 + wc + nt * 16 + col16;
          float ang = p * freqr[nt];
          float sn = __sinf(ang), cs = __cosf(ang);
          float val = acc[mt][nt][r];
          float oth = __shfl_xor(val, 1);
          C[(size_t)row * D_ + col] = f2bf((val * cs + oth * sgn * sn) * qs);
        }
      }
  }
}

// ---------------------------------------------------------------------------
// Wo projection GEMM. 64x64 tiles -> 1024 blocks, 16 KB LDS, bounds(256,8).
// (unchanged from R5)
// ---------------------------------------------------------------------------
__global__ __launch_bounds__(256, 8)
void gemm_wo(const unsigned short* __restrict__ A,
             const unsigned short* __restrict__ W,
             float* __restrict__ C)
{
  __shared__ unsigned short As[64 * 64];    // 8 KB
  __shared__ unsigned short Bs[64 * 64];    // 8 KB

  const int flat = blockIdx.y * 16 + blockIdx.x;  // 0..1023
  const int xcd  = flat & 7;
  const int u    = flat >> 3;                     // 0..127
  const int by   = xcd * 8 + (u & 7);             // 0..63
  const int bx   = u >> 3;                        // 0..15

  const int tid   = threadIdx.x;
  const int wave  = tid >> 6;
  const int lane  = tid & 63;
  const int quad  = lane >> 4;
  const int col16 = lane & 15;
  const int row0  = by * 64;
  const int col0  = bx * 64;
  const int wr    = (wave >> 1) * 32;
  const int wc    = (wave & 1) * 32;

  const int srow = wave * 8 + (lane >> 3);
  const int scol = ((lane & 7) ^ ((lane >> 3) & 7)) * 8;
  const unsigned short* gA = A + (size_t)(row0 + srow) * D_ + scol;
  const unsigned short* gB = W + (size_t)(col0 + srow) * D_ + scol;

  f32x4 acc[2][2];
  #pragma unroll
  for (int mt = 0; mt < 2; ++mt)
    #pragma unroll
    for (int nt = 0; nt < 2; ++nt)
      #pragma unroll
      for (int r = 0; r < 4; ++r) acc[mt][nt][r] = 0.f;

  for (int k0 = 0; k0 < D_; k0 += 64) {
    __syncthreads();
    #pragma unroll
    for (int p = 0; p < 2; ++p) {
      gload_lds16(gA + (size_t)(p * 32) * D_ + k0, &As[(p * 32 + wave * 8) * 64]);
      gload_lds16(gB + (size_t)(p * 32) * D_ + k0, &Bs[(p * 32 + wave * 8) * 64]);
    }
    __syncthreads();

    #pragma unroll
    for (int h = 0; h < 2; ++h) {
      const int jo = ((h * 4 + quad) ^ (col16 & 7)) * 8;
      bf16x8 af[2], bfr[2];
      #pragma unroll
      for (int mt = 0; mt < 2; ++mt)
        af[mt] = *(const bf16x8*)&As[(wr + mt * 16 + col16) * 64 + jo];
      #pragma unroll
      for (int nt = 0; nt < 2; ++nt)
        bfr[nt] = *(const bf16x8*)&Bs[(wc + nt * 16 + col16) * 64 + jo];

      #pragma unroll
      for (int mt = 0; mt < 2; ++mt)
        #pragma unroll
        for (int nt = 0; nt < 2; ++nt)
          acc[mt][nt] = __builtin_amdgcn_mfma_f32_16x16x32_bf16(
              af[mt], bfr[nt], acc[mt][nt], 0, 0, 0);
    }
  }

  #pragma unroll
  for (int mt = 0; mt < 2; ++mt)
    #pragma unroll
    for (int r = 0; r < 4; ++r) {
      int row = row0 + wr + mt * 16 + quad * 4 + r;
      #pragma unroll
      for (int nt = 0; nt < 2; ++nt) {
        int col = col0 + wc + nt * 16 + col16;
        C[(size_t)row * D_ + col] = acc[mt][nt][r];
      }
    }
}

// ---------------------------------------------------------------------------
// Flash attention R8: INDEPENDENT 256-thread blocks (4 row-waves, no parity
// split, no combine). One q-tile (64 rows) per block; block processes ALL its
// key-halves serially from single 8 KB K / 8 KB V slots (stage -> drain ->
// compute; R0/R1 proved drain vs counted-prefetch is neutral when TLP covers).
// LDS 25 KB -> 6 blocks/CU = 24 waves/CU, ALL 1024 blocks resident from t=0
// (perfect load balance). No cross-parity lockstep: barriers couple only the
// 4 waves sharing the K/V slots. Softmax restructured per-nb to shrink live
// registers so bounds(256,8) holds VGPR<=64 (8-waves/SIMD quantum).
// ---------------------------------------------------------------------------
__global__ __launch_bounds__(256, 8)
void attn_mfma(const unsigned short* __restrict__ Q,
               const unsigned short* __restrict__ K,
               const unsigned short* __restrict__ Vt,
               unsigned short* __restrict__ O)
{
  const int f   = blockIdx.x;          // 0..1023
  const int qt  = 31 - (f >> 5);       // big q-tiles dispatched first
  const int bh  = f & 31;              // xcd = f&7 ~ bh&7 -> L2 locality
  const int b   = bh >> 4, h = bh & 15;

  const int tid  = threadIdx.x;
  const int w    = tid >> 6;           // row-wave 0..3
  const int lane = tid & 63;
  const int quad = lane >> 4;
  const int col  = lane & 15;
  const int qlocal = w * 16 + col;

  __shared__ unsigned short Ks[4096];                    // 64-key K slot, 8 KB
  __shared__ unsigned short Vs[4096];                    // 64-key V slot, 8 KB
  __shared__ __align__(16) unsigned short Pl[4][16][72]; // 9 KB, per-wave P

  const size_t qkbase = (size_t)b * S_ * D_ + (size_t)h * DK_;
  const size_t vtbase = (size_t)bh * DK_ * S_;

  const int qrow = qt * 64 + qlocal;
  bf16x8 qf[2];
  qf[0] = *(const bf16x8*)(Q + qkbase + (size_t)qrow * D_ + quad * 8);
  qf[1] = *(const bf16x8*)(Q + qkbase + (size_t)qrow * D_ + 32 + quad * 8);

  // staging: wave covers rows w*16..w*16+15 of each slot (2 gloads each).
  const int lr8 = lane >> 3;                       // 0..7 row within 8
  const int sj  = ((lane & 7) ^ (lr8 & 7)) * 8;    // swizzled source octet

  f32x4 Oacc[4];
  #pragma unroll
  for (int nb = 0; nb < 4; ++nb)
    #pragma unroll
    for (int r = 0; r < 4; ++r) Oacc[nb][r] = 0.f;
  float l_i = 0.f;

  const int jx = quad ^ (col & 7);
  unsigned short (*Plw)[72] = Pl[w];

  for (int g = 0; g <= qt; ++g) {
    // ---- stage K,V half g into the (now free) slots ----
    {
      const unsigned short* sK =
          K + qkbase + (size_t)(g * 64 + w * 16 + lr8) * D_ + sj;
      const unsigned short* sV =
          Vt + vtbase + (size_t)(w * 16 + lr8) * S_ + g * 64 + sj;
      #pragma unroll
      for (int pp = 0; pp < 2; ++pp) {
        gload_lds16(sK + (size_t)(pp * 8) * D_, &Ks[(w * 16 + pp * 8) * 64]);
        gload_lds16(sV + (size_t)(pp * 8) * S_, &Vs[(w * 16 + pp * 8) * 64]);
      }
    }
    asm volatile("s_waitcnt vmcnt(0)" ::: "memory");   // own DMAs landed
    __builtin_amdgcn_sched_barrier(0);
    __builtin_amdgcn_s_barrier();                      // all waves' DMAs landed
    __builtin_amdgcn_sched_barrier(0);

    // ---- QK^T + softmax, per 16-key group (small register footprint) ----
    const bool dg = (g == qt);
    float rsum = 0.f;
    #pragma unroll
    for (int nb = 0; nb < 4; ++nb) {
      const int s0 = (nb * 16 + col) * 8 + jx;
      bf16x8 ka0 = *(const bf16x8*)(Ks + s0 * 8);
      bf16x8 ka1 = *(const bf16x8*)(Ks + (s0 ^ 4) * 8);
      f32x4 a = {-24.f, -24.f, -24.f, -24.f};          // fixed-max bias
      a = __builtin_amdgcn_mfma_f32_16x16x32_bf16(ka0, qf[0], a, 0, 0, 0);
      a = __builtin_amdgcn_mfma_f32_16x16x32_bf16(ka1, qf[1], a, 0, 0, 0);
      if (dg) {
        #pragma unroll
        for (int r = 0; r < 4; ++r)
          if (nb * 16 + quad * 4 + r > qlocal) a[r] = -1e30f;
      }
      #pragma unroll
      for (int r = 0; r < 4; ++r) {
        a[r] = fast_exp2(a[r]);
        rsum += a[r];
      }
      uint2 pk;
      pk.x = pack_trunc(a[0], a[1]);
      pk.y = pack_trunc(a[2], a[3]);
      *(uint2*)&Plw[col][nb * 16 + quad * 4] = pk;
    }
    rsum += __shfl_xor(rsum, 16);
    rsum += __shfl_xor(rsum, 32);
    l_i += rsum;

    // ---- PV from V slot (P via wave-private LDS round-trip) ----
    bf16x8 pf0 = *(const bf16x8*)&Plw[col][quad * 8];
    bf16x8 pf1 = *(const bf16x8*)&Plw[col][32 + quad * 8];
    __builtin_amdgcn_s_setprio(1);
    #pragma unroll
    for (int nb = 0; nb < 4; ++nb) {
      const int s0 = (nb * 16 + col) * 8 + jx;
      bf16x8 va0 = *(const bf16x8*)(Vs + s0 * 8);
      bf16x8 va1 = *(const bf16x8*)(Vs + (s0 ^ 4) * 8);
      Oacc[nb] = __builtin_amdgcn_mfma_f32_16x16x32_bf16(va0, pf0, Oacc[nb], 0, 0, 0);
      Oacc[nb] = __builtin_amdgcn_mfma_f32_16x16x32_bf16(va1, pf1, Oacc[nb], 0, 0, 0);
    }
    __builtin_amdgcn_s_setprio(0);

    __builtin_amdgcn_sched_barrier(0);
    __builtin_amdgcn_s_barrier();    // all K/V reads done -> slots reusable
    __builtin_amdgcn_sched_barrier(0);
  }

  // ---- epilogue: no combine needed, each wave owns its rows ----
  const float inv = 1.0f / l_i;
  #pragma unroll
  for (int nb = 0; nb < 4; ++nb) {
    int d = nb * 16 + quad * 4;
    ushort4 oa;
    oa.x = f2bf(Oacc[nb][0] * inv);
    oa.y = f2bf(Oacc[nb][1] * inv);
    oa.z = f2bf(Oacc[nb][2] * inv);
    oa.w = f2bf(Oacc[nb][3] * inv);
    *(ushort4*)(O + (size_t)b * S_ * D_ + (size_t)qrow * D_ + h * DK_ + d) = oa;
  }
}

// ---------------------------------------------------------------------------
extern "C" void kernel_launch(void* const* d_in, const int* in_sizes, int n_in,
                              void* d_out, int out_size, void* d_ws, size_t ws_size,
                              hipStream_t stream)
{
  const float* x  = (const float*)d_in[0];
  const float* Wq = (const float*)d_in[1];
  const float* Wk = (const float*)d_in[2];
  const float* Wv = (const float*)d_in[3];
  const float* Wo = (const float*)d_in[4];
  const int*   tp = (const int*)d_in[5];
  float* out = (float*)d_out;

  const size_t NTOK = (size_t)B_ * S_ * D_;     // 4,194,304 elements
  const size_t NW   = (size_t)D_ * D_;          // 1,048,576
  unsigned short* qh  = (unsigned short*)d_ws;  // bf16 [B,S,D]
  unsigned short* kh  = qh + NTOK;
  unsigned short* vt  = kh + NTOK;              // bf16 [B*H, 64, S]
  unsigned short* xb  = vt + NTOK;              // bf16 [B,S,D]; reused as ab
  unsigned short* wqb = xb + NTOK;
  unsigned short* wkb = wqb + NW;
  unsigned short* wvb = wkb + NW;
  unsigned short* wob = wvb + NW;
  unsigned short* ab  = xb;                     // alias: xb dead after QKV gemm

  // fp32 -> bf16 casts
  cast5_bf16<<<dim3(4096), 256, 0, stream>>>(
      x, Wq, Wk, Wv, Wo, xb, wqb, wkb, wvb, wob);

  // fused QKV projection + RoPE + Q-scale + direct-V^T, 64x128 tiles (R5)
  gemm_qkv<<<dim3(8, 64, 3), 256, 0, stream>>>(
      xb, wqb, wkb, wvb, qh, kh, vt, tp);

  // independent-block flash attention (fixed-max softmax) -> bf16 ab
  attn_mfma<<<dim3(32 * 32), 256, 0, stream>>>(qh, kh, vt, ab);

  // output projection, 64x64 tiles -> fp32 out
  gemm_wo<<<dim3(16, 64), 256, 0, stream>>>(ab, wob, out);
}